// Round 14
// baseline (375.446 us; speedup 1.0000x reference)
//
#include <hip/hip_runtime.h>
#include <hip/hip_bf16.h>
#include <cstdint>

#define IN_CH 512
#define HC    512   // HEADS*CH
#define HEADS 8
#define NPACK 1024  // W_l | W_r packed

typedef __attribute__((ext_vector_type(8))) short bf16x8;
typedef __attribute__((ext_vector_type(8))) ushort u16x8;
typedef __attribute__((ext_vector_type(4))) float f32x4;
typedef __attribute__((ext_vector_type(2))) float f32x2;
typedef const __attribute__((address_space(1))) uint8_t* gaddr_t;
typedef __attribute__((address_space(3))) uint8_t* laddr_t;

__device__ inline ushort f2bf(float f) {  // round-to-nearest-even
  uint32_t u = __float_as_uint(f);
  return (ushort)((u + 0x7fffu + ((u >> 16) & 1u)) >> 16);
}
__device__ inline float bf2f(ushort u) {
  return __uint_as_float(((uint32_t)u) << 16);
}

// ---- fp8 e4m3 (OCP) encode/decode: HW cvt ops on gfx950, ALU fallback ------
#if defined(__has_builtin)
#if __has_builtin(__builtin_amdgcn_cvt_pk_f32_fp8) && __has_builtin(__builtin_amdgcn_cvt_pk_fp8_f32)
#define HAVE_HW_FP8 1
#endif
#if __has_builtin(__builtin_elementwise_max)
#define HAVE_EW_MAX 1
#endif
#endif

__device__ __forceinline__ float fp8_decode_sw(uint32_t v) {
  const uint32_t t = v & 0x7fu;
  float m;
  if (t >= 8u) m = __uint_as_float((((t >> 3) + 120u) << 23) | ((t & 7u) << 20));
  else m = (float)t * 0.001953125f;  // subnormal: t * 2^-9
  return (v & 0x80u) ? -m : m;
}
__device__ __forceinline__ uint8_t fp8_encode_sw(float f) {
  const uint32_t b = __float_as_uint(f);
  const uint32_t s = (b >> 24) & 0x80u;
  uint32_t a = b & 0x7fffffffu;
  if (a >= 0x43e00000u) return (uint8_t)(s | 0x7eu);  // saturate to 448
  if (a < 0x3c800000u) {                              // subnormal (< 2^-6)
    const int qi = (int)(__uint_as_float(a) * 512.0f + 0.5f);
    return (uint8_t)(s | (qi >= 8 ? 8u : (uint32_t)qi));
  }
  const uint32_t r = a + 0x7ffffu + ((a >> 20) & 1u);  // RNE to 3-bit mantissa
  const uint32_t e = r >> 23;
  if (e > 135u) return (uint8_t)(s | 0x7eu);
  return (uint8_t)(s | ((e - 120u) << 3) | ((r >> 20) & 7u));
}

// decode 2 fp8 (low/high half-word of u) straight into a packed f32x2.
// HI must be a compile-time constant: the builtin requires an immediate.
template<bool HI>
__device__ __forceinline__ f32x2 fp8x2_dec(uint32_t u) {
#ifdef HAVE_HW_FP8
  return __builtin_amdgcn_cvt_pk_f32_fp8(u, HI);
#else
  const uint32_t w = HI ? (u >> 16) : u;
  f32x2 r;
  r.x = fp8_decode_sw(w & 0xffu);
  r.y = fp8_decode_sw((w >> 8) & 0xffu);
  return r;
#endif
}
__device__ __forceinline__ uint8_t f32_to_fp8(float f) {
#ifdef HAVE_HW_FP8
  return (uint8_t)(__builtin_amdgcn_cvt_pk_fp8_f32(f, f, 0, false) & 0xff);
#else
  return fp8_encode_sw(f);
#endif
}
// pack two f32x2 -> 4 fp8 bytes in one u32
__device__ __forceinline__ uint32_t fp8x4_pack(f32x2 a, f32x2 b) {
#ifdef HAVE_HW_FP8
  uint32_t w = __builtin_amdgcn_cvt_pk_fp8_f32(a.x, a.y, 0, false);
  w = __builtin_amdgcn_cvt_pk_fp8_f32(b.x, b.y, w, true);
  return w;
#else
  return (uint32_t)fp8_encode_sw(a.x) | ((uint32_t)fp8_encode_sw(a.y) << 8) |
         ((uint32_t)fp8_encode_sw(b.x) << 16) | ((uint32_t)fp8_encode_sw(b.y) << 24);
#endif
}

// packed 2xf32 max -> v_pk_max_f32
__device__ __forceinline__ f32x2 pk_max(f32x2 a, f32x2 b) {
#ifdef HAVE_EW_MAX
  return __builtin_elementwise_max(a, b);
#else
  f32x2 r; r.x = fmaxf(a.x, b.x); r.y = fmaxf(a.y, b.y); return r;
#endif
}

// DPP cross-lane add: pure-VALU butterfly step.
template<int CTRL>
__device__ __forceinline__ float dpp_add(float s) {
  const int t = __builtin_amdgcn_update_dpp(0, __float_as_int(s), CTRL, 0xf, 0xf, true);
  return s + __int_as_float(t);
}

// ---- fused prep: cast x->bf16 | pack W^T bf16 | hist(dst) | hist(label s) --
__global__ void prep(const float* __restrict__ x, ushort* __restrict__ xb,
                     const float* __restrict__ Wl, const float* __restrict__ Wr,
                     ushort* __restrict__ bt,
                     const int* __restrict__ ei, int* __restrict__ counts,
                     const int* __restrict__ eli, int* __restrict__ counts2,
                     int n4, int E, int EL, int nbc, int nbp, int nbh) {
  const int b = blockIdx.x;
  if (b < nbc) {
    const int i = b * 256 + threadIdx.x;
    if (i < n4) {
      const float4 v = ((const float4*)x)[i];
      ushort4 o;
      o.x = f2bf(v.x); o.y = f2bf(v.y); o.z = f2bf(v.z); o.w = f2bf(v.w);
      ((ushort4*)xb)[i] = o;
    }
  } else if (b < nbc + nbp) {
    const int i = (b - nbc) * 256 + threadIdx.x;
    if (i < NPACK * IN_CH) {
      const int n = i >> 9, k = i & 511;
      const float v = (n < HC) ? Wl[(size_t)k * HC + n] : Wr[(size_t)k * HC + (n - HC)];
      bt[i] = f2bf(v);
    }
  } else if (b < nbc + nbp + nbh) {
    const int e = (b - nbc - nbp) * 256 + threadIdx.x;
    if (e < E) atomicAdd(&counts[ei[E + e]], 1);
  } else {
    const int e = (b - nbc - nbp - nbh) * 256 + threadIdx.x;
    if (e < EL) atomicAdd(&counts2[eli[e]], 1);
  }
}

// ---- bf16 MFMA GEMM: [M,1024] = xb[M,512] @ Bt^T ---------------------------
// R14 (kept, MATCHED): 256x128 tiles, 8 waves, 3-buf counted-vmcnt ring,
// XCD-chunk swizzle (632 = 8*79 bijective).
__global__ __launch_bounds__(512) void gemm_mfma(
    const ushort* __restrict__ xb, const ushort* __restrict__ bt,
    uint8_t* __restrict__ xl8, ushort* __restrict__ xrb, int M) {
  __shared__ __align__(16) ushort As[3][256 * 32];  // 48 KB ring
  __shared__ __align__(16) ushort Bs[3][128 * 32];  // 24 KB ring
  const int sw  = (blockIdx.x & 7) * 79 + (blockIdx.x >> 3);
  const int row0 = (sw >> 3) * 256;
  const int col0 = (sw & 7) * 128;
  const int wave = threadIdx.x >> 6, lane = threadIdx.x & 63;
  const int quad = lane >> 4, m16 = lane & 15;
  const int wrow = (wave >> 1) * 64;
  const int wcol = (wave & 1) * 64;
  const int srow = lane >> 2;
  const int scol = (lane & 3) * 8;
  const f32x4 zero = {0.f, 0.f, 0.f, 0.f};
  f32x4 acc[4][4];
  #pragma unroll
  for (int i = 0; i < 4; ++i)
    #pragma unroll
    for (int j = 0; j < 4; ++j) acc[i][j] = zero;

  auto stage = [&](int buf, int kt) {  // 3 VMEM instrs per wave
    const int k0 = kt * 32;
    const int r = wave * 16 + srow;
    const ushort* ga0 = xb + (size_t)(row0 + r) * IN_CH + k0 + scol;
    __builtin_amdgcn_global_load_lds((gaddr_t)ga0, (laddr_t)(&As[buf][(wave * 16) * 32]), 16, 0, 0);
    const ushort* ga1 = xb + (size_t)(row0 + 128 + r) * IN_CH + k0 + scol;
    __builtin_amdgcn_global_load_lds((gaddr_t)ga1, (laddr_t)(&As[buf][(128 + wave * 16) * 32]), 16, 0, 0);
    const ushort* gb = bt + (size_t)(col0 + r) * IN_CH + k0 + scol;
    __builtin_amdgcn_global_load_lds((gaddr_t)gb, (laddr_t)(&Bs[buf][(wave * 16) * 32]), 16, 0, 0);
  };
  auto compute = [&](int buf) {
    bf16x8 af[4], bfr[4];
    #pragma unroll
    for (int i = 0; i < 4; ++i)
      af[i] = *(const bf16x8*)(&As[buf][(wrow + i * 16 + m16) * 32 + quad * 8]);
    #pragma unroll
    for (int j = 0; j < 4; ++j)
      bfr[j] = *(const bf16x8*)(&Bs[buf][(wcol + j * 16 + m16) * 32 + quad * 8]);
    #pragma unroll
    for (int i = 0; i < 4; ++i)
      #pragma unroll
      for (int j = 0; j < 4; ++j)
        acc[i][j] = __builtin_amdgcn_mfma_f32_16x16x32_bf16(af[i], bfr[j], acc[i][j], 0, 0, 0);
  };

  stage(0, 0);
  stage(1, 1);
  int buf = 0;
  for (int kt = 0; kt <= 13; ++kt) {
    asm volatile("s_waitcnt vmcnt(3)" ::: "memory");
    __builtin_amdgcn_s_barrier();
    int nbuf = buf + 2; if (nbuf >= 3) nbuf -= 3;
    stage(nbuf, kt + 2);
    compute(buf);
    ++buf; if (buf == 3) buf = 0;
  }
  asm volatile("s_waitcnt vmcnt(3)" ::: "memory");
  __builtin_amdgcn_s_barrier();
  compute(buf);
  ++buf; if (buf == 3) buf = 0;
  asm volatile("s_waitcnt vmcnt(0)" ::: "memory");
  __builtin_amdgcn_s_barrier();
  compute(buf);

  const bool isL = (col0 < HC);
  if (isL) {
    #pragma unroll
    for (int i = 0; i < 4; ++i) {
      const int r = row0 + wrow + i * 16 + quad * 4;
      #pragma unroll
      for (int j = 0; j < 4; ++j) {
        const int cg = col0 + wcol + j * 16 + m16;
        #pragma unroll
        for (int t = 0; t < 4; ++t) {
          const int rr = r + t;
          if (rr < M) xl8[(size_t)rr * HC + cg] = f32_to_fp8(acc[i][j][t]);
        }
      }
    }
  } else {
    const int cbase = col0 - HC;
    #pragma unroll
    for (int i = 0; i < 4; ++i) {
      const int r = row0 + wrow + i * 16 + quad * 4;
      #pragma unroll
      for (int j = 0; j < 4; ++j) {
        const int cg = cbase + wcol + j * 16 + m16;
        #pragma unroll
        for (int t = 0; t < 4; ++t) {
          const int rr = r + t;
          if (rr < M) xrb[(size_t)rr * HC + cg] = f2bf(acc[i][j][t]);
        }
      }
    }
  }
}

// ---- fused dual-CSR exclusive scan (standalone; merged version regressed) --
__global__ __launch_bounds__(256) void scan_fused(
    const int* __restrict__ cA, int* __restrict__ oA, int* __restrict__ curA,
    int* __restrict__ fA,
    const int* __restrict__ cB, int* __restrict__ oB, int* __restrict__ curB,
    int* __restrict__ fB, int Nn, int nb) {
  const int half = (blockIdx.x >= nb) ? 1 : 0;
  const int blk  = blockIdx.x - half * nb;
  const int* counts = half ? cB : cA;
  int* offsets = half ? oB : oA;
  int* cursor  = half ? curB : curA;
  int* flags   = half ? fB : fA;
  __shared__ int tmp[256];
  __shared__ int sPref;
  const int t = threadIdx.x;
  const int i = blk * 256 + t;
  const int v = (i < Nn) ? counts[i] : 0;
  tmp[t] = v;
  __syncthreads();
  for (int d = 1; d < 256; d <<= 1) {
    int add = (t >= d) ? tmp[t - d] : 0;
    __syncthreads();
    tmp[t] += add;
    __syncthreads();
  }
  if (t == 0) atomicExch(&flags[blk], tmp[255] + 1);  // publish aggregate
  if (t < 64) {
    int s = 0;
    for (int b = t; b < blk; b += 64) {
      int f;
      do { f = atomicOr(&flags[b], 0); } while (f == 0);
      s += f - 1;
    }
    #pragma unroll
    for (int off = 32; off > 0; off >>= 1) s += __shfl_down(s, off, 64);
    if (t == 0) sPref = s;
  }
  __syncthreads();
  const int pref = sPref;
  if (i < Nn) {
    const int o = tmp[t] - v + pref;  // exclusive prefix
    offsets[i] = o;
    cursor[i] = o;
  }
}

// 1-edge-per-thread fill (1642 blocks); label CSR packed int2.
__global__ void csr_fill(const int* __restrict__ ei, int* __restrict__ cursor,
                         int* __restrict__ csr_src,
                         const int* __restrict__ eli, int* __restrict__ cursor2,
                         int2* __restrict__ csr_te, int E, int EL, int nbE) {
  const int b = blockIdx.x;
  if (b < nbE) {
    const int e = b * 256 + threadIdx.x;
    if (e < E) {
      const int pos = atomicAdd(&cursor[ei[E + e]], 1);
      csr_src[pos] = ei[e];
    }
  } else {
    const int e = (b - nbE) * 256 + threadIdx.x;
    if (e < EL) {
      const int pos = atomicAdd(&cursor2[eli[e]], 1);
      csr_te[pos] = make_int2(eli[EL + e], e);
    }
  }
}

// ------- fused GATv2 + BN stats: logits/softmax/agg + channel sums ----------
// R20: bn_stats FUSED into the epilogue -- the pre-quantization f32 values are
// already in registers, so the 10.2MB agg8 re-read + one dispatch disappear.
// Per block: LDS-reduce 4 waves' channel sums, 1024 global atomics, last-block
// (done-counter) computes aScale/bShift. deg==0/early-return became guards
// (barrier convergence). Grid = exactly Nn/4 = 5000 blocks, no tail.
__global__ __launch_bounds__(256) void gatv2_agg(
    const uint8_t* __restrict__ xl8, const ushort* xrb, const float* __restrict__ att,
    const int* __restrict__ offsets, const int* __restrict__ counts,
    const int* __restrict__ csr_src, uint8_t* __restrict__ agg8,
    float* __restrict__ gsum, float* __restrict__ gsq, int* __restrict__ ctr,
    const float* __restrict__ gamma, const float* __restrict__ beta,
    float* __restrict__ aScale, float* __restrict__ bShift, float invN, int Nn) {
  __shared__ float sSum[HC];
  __shared__ float sSq[HC];
  const int node = blockIdx.x * 4 + (threadIdx.x >> 6);
  const int lane = threadIdx.x & 63;
  const int tid  = threadIdx.x;
  sSum[tid] = 0.f; sSum[tid + 256] = 0.f;
  sSq[tid]  = 0.f; sSq[tid + 256]  = 0.f;

  f32x2 v2[4] = {{0.f, 0.f}, {0.f, 0.f}, {0.f, 0.f}, {0.f, 0.f}};  // final values
  const bool active = (node < Nn);
  if (active) {
    const int start = offsets[node];
    const int deg   = counts[node];
    uint2* pd = (uint2*)(agg8 + (size_t)node * HC + lane * 8);
    if (deg == 0) {
      const uint2 z = {0u, 0u};
      *pd = z;  // v2 stays zero; still contributes (zeros) to BN stats
    } else {
      f32x2 rv2[4], tv2[4];
      {
        const u16x8 ur = *(const u16x8*)(xrb + (size_t)node * HC + lane * 8);
        #pragma unroll
        for (int c = 0; c < 4; ++c) {
          rv2[c].x = bf2f((ushort)ur[2 * c]);
          rv2[c].y = bf2f((ushort)ur[2 * c + 1]);
        }
        const float4* pa = (const float4*)(att + lane * 8);
        const float4 t0 = pa[0], t1 = pa[1];
        tv2[0].x = t0.x; tv2[0].y = t0.y;
        tv2[1].x = t0.z; tv2[1].y = t0.w;
        tv2[2].x = t1.x; tv2[2].y = t1.y;
        tv2[3].x = t1.z; tv2[3].y = t1.w;
      }
      f32x2 acc2[4] = {{0.f, 0.f}, {0.f, 0.f}, {0.f, 0.f}, {0.f, 0.f}};
      float densum = 0.f;
      const int* ps = csr_src + start;
      auto row = [&](int idx) {
        return *(const uint2*)(xl8 + (size_t)ps[idx] * HC + lane * 8);
      };
      auto body = [&](const uint2 cur) {
        f32x2 a0 = fp8x2_dec<false>(cur.x);
        f32x2 a1 = fp8x2_dec<true>(cur.x);
        f32x2 a2 = fp8x2_dec<false>(cur.y);
        f32x2 a3 = fp8x2_dec<true>(cur.y);
        f32x2 v, s2;
        v = a0 + rv2[0]; s2  = pk_max(v, 0.2f * v) * tv2[0];  // leaky_relu
        v = a1 + rv2[1]; s2 += pk_max(v, 0.2f * v) * tv2[1];
        v = a2 + rv2[2]; s2 += pk_max(v, 0.2f * v) * tv2[2];
        v = a3 + rv2[3]; s2 += pk_max(v, 0.2f * v) * tv2[3];
        float s = s2.x + s2.y;
        s = dpp_add<0xB1>(s);    // xor1
        s = dpp_add<0x4E>(s);    // xor2
        s = dpp_add<0x141>(s);   // xor4 (row_half_mirror)
        const float ea = __expf(s);
        densum += ea;
        const f32x2 eav = {ea, ea};
        acc2[0] += eav * a0;
        acc2[1] += eav * a1;
        acc2[2] += eav * a2;
        acc2[3] += eav * a3;
      };

      // depth-2 prefetch (measured best, R8)
      uint2 b0 = {}, b1 = {};
      b0 = row(0);
      if (deg > 1) b1 = row(1);
      int i = 0;
      for (; i + 2 <= deg; i += 2) {
        const uint2 c0 = b0;
        if (i + 2 < deg) b0 = row(i + 2);
        const uint2 c1 = b1;
        if (i + 3 < deg) b1 = row(i + 3);
        body(c0);
        body(c1);
      }
      if (i < deg) body(b0);

      const float inv = 1.0f / (densum + 1e-16f);
      const f32x2 iv = {inv, inv};
      v2[0] = acc2[0] * iv; v2[1] = acc2[1] * iv;
      v2[2] = acc2[2] * iv; v2[3] = acc2[3] * iv;
      uint2 pack;
      pack.x = fp8x4_pack(v2[0], v2[1]);
      pack.y = fp8x4_pack(v2[2], v2[3]);
      *pd = pack;
    }
  }
  // ---- BN stats epilogue (all threads converge here) ----
  __syncthreads();  // LDS zeroing complete
  if (active) {
    #pragma unroll
    for (int p = 0; p < 4; ++p) {
      const int ch = lane * 8 + 2 * p;
      atomicAdd(&sSum[ch],     v2[p].x);
      atomicAdd(&sSum[ch + 1], v2[p].y);
      atomicAdd(&sSq[ch],      v2[p].x * v2[p].x);
      atomicAdd(&sSq[ch + 1],  v2[p].y * v2[p].y);
    }
  }
  __syncthreads();
  atomicAdd(&gsum[tid],       sSum[tid]);
  atomicAdd(&gsum[tid + 256], sSum[tid + 256]);
  atomicAdd(&gsq[tid],        sSq[tid]);
  atomicAdd(&gsq[tid + 256],  sSq[tid + 256]);
  __shared__ int isLast;
  __syncthreads();
  if (tid == 0) {
    __threadfence();
    isLast = (atomicAdd(ctr, 1) == (int)gridDim.x - 1) ? 1 : 0;
  }
  __syncthreads();
  if (isLast) {
    #pragma unroll
    for (int k = 0; k < 2; ++k) {
      const int c = tid + k * 256;
      const float sum = atomicAdd(&gsum[c], 0.0f);  // coherent read
      const float sq  = atomicAdd(&gsq[c], 0.0f);
      const float m = sum * invN;
      const float var = sq * invN - m * m;
      const float rs = rsqrtf(var + 1e-5f);
      const float a = rs * gamma[c];
      aScale[c] = a;
      bShift[c] = beta[c] - m * a;
    }
  }
}

// ------------- source-grouped link scoring: fp8 agg + inline BN -------------
// R19 (kept): gathers agg8 (8 B/lane) + packed-f32 BN+ReLU+dot.
__global__ __launch_bounds__(256) void score_g(
    const uint8_t* __restrict__ agg8, const float* __restrict__ aScale,
    const float* __restrict__ bShift, const int* __restrict__ off2,
    const int* __restrict__ cnt2, const int2* __restrict__ csr_te,
    float* __restrict__ out, int Nn) {
  const int node = blockIdx.x * 4 + (threadIdx.x >> 6);
  const int lane = threadIdx.x & 63;
  if (node >= Nn) return;
  const int start = off2[node];
  const int deg   = cnt2[node];
  if (deg == 0) return;
  const f32x2 z2 = {0.f, 0.f};
  f32x2 aS2[4], bS2[4], ys2[4];
  {
    const float4* pa = (const float4*)(aScale + lane * 8);
    const float4 a0 = pa[0], a1 = pa[1];
    aS2[0].x=a0.x; aS2[0].y=a0.y; aS2[1].x=a0.z; aS2[1].y=a0.w;
    aS2[2].x=a1.x; aS2[2].y=a1.y; aS2[3].x=a1.z; aS2[3].y=a1.w;
    const float4* pb = (const float4*)(bShift + lane * 8);
    const float4 c0 = pb[0], c1 = pb[1];
    bS2[0].x=c0.x; bS2[0].y=c0.y; bS2[1].x=c0.z; bS2[1].y=c0.w;
    bS2[2].x=c1.x; bS2[2].y=c1.y; bS2[3].x=c1.z; bS2[3].y=c1.w;
    const uint2 us = *(const uint2*)(agg8 + (size_t)node * HC + lane * 8);
    ys2[0] = pk_max(z2, fp8x2_dec<false>(us.x) * aS2[0] + bS2[0]);
    ys2[1] = pk_max(z2, fp8x2_dec<true>(us.x)  * aS2[1] + bS2[1]);
    ys2[2] = pk_max(z2, fp8x2_dec<false>(us.y) * aS2[2] + bS2[2]);
    ys2[3] = pk_max(z2, fp8x2_dec<true>(us.y)  * aS2[3] + bS2[3]);
  }
  const int2* pte = csr_te + start;
  auto row = [&](int idx) {
    return *(const uint2*)(agg8 + (size_t)pte[idx].x * HC + lane * 8);
  };
  auto emit = [&](const uint2 ut, int eid) {
    f32x2 s2;
    s2  = ys2[0] * pk_max(z2, fp8x2_dec<false>(ut.x) * aS2[0] + bS2[0]);
    s2 += ys2[1] * pk_max(z2, fp8x2_dec<true>(ut.x)  * aS2[1] + bS2[1]);
    s2 += ys2[2] * pk_max(z2, fp8x2_dec<false>(ut.y) * aS2[2] + bS2[2]);
    s2 += ys2[3] * pk_max(z2, fp8x2_dec<true>(ut.y)  * aS2[3] + bS2[3]);
    float s = s2.x + s2.y;
    s = dpp_add<0xB1>(s);    // xor1
    s = dpp_add<0x4E>(s);    // xor2
    s = dpp_add<0x141>(s);   // xor4 (row_half_mirror)
    s = dpp_add<0x140>(s);   // xor8 (row_mirror) -> all lanes hold row16 sum
    s = dpp_add<0x142>(s);   // row_bcast15: row1+=row0, row3+=row2
    s = dpp_add<0x143>(s);   // row_bcast31: hi half += lane31 -> lane63 total
    if (lane == 63) out[eid] = s;
  };
  uint2 b0 = {}, b1 = {};
  b0 = row(0);
  if (deg > 1) b1 = row(1);
  int j = 0;
  for (; j + 2 <= deg; j += 2) {
    const uint2 c0 = b0;
    if (j + 2 < deg) b0 = row(j + 2);
    const uint2 c1 = b1;
    if (j + 3 < deg) b1 = row(j + 3);
    emit(c0, pte[j].y);
    emit(c1, pte[j + 1].y);
  }
  if (j < deg) emit(b0, pte[j].y);
}

extern "C" void kernel_launch(void* const* d_in, const int* in_sizes, int n_in,
                              void* d_out, int out_size, void* d_ws, size_t ws_size,
                              hipStream_t stream) {
  const float* x     = (const float*)d_in[0];
  const int*   ei    = (const int*)d_in[1];
  const int*   eli   = (const int*)d_in[2];
  const float* W_l   = (const float*)d_in[3];
  const float* W_r   = (const float*)d_in[4];
  const float* att   = (const float*)d_in[5];
  // d_in[6] = bias: cancels exactly inside train-mode BatchNorm -> unused.
  const float* gamma = (const float*)d_in[7];
  const float* beta  = (const float*)d_in[8];
  float* out = (float*)d_out;

  const int Nn = in_sizes[0] / IN_CH;  // 20000
  const int E  = in_sizes[1] / 2;      // 320000
  const int EL = in_sizes[2] / 2;      // 100000

  // ---- workspace layout -----------------------------------------------------
  uint8_t* xl8 = (uint8_t*)d_ws;                   // Nn*HC fp8 (region sized Nn*HC*2B)
  ushort* xrb = (ushort*)d_ws + (size_t)Nn * HC;   // Nn*HC bf16 (gatv2 input)
  ushort* xbf = xrb + (size_t)Nn * HC;             // Nn*IN_CH bf16 (dead after gemm)
  ushort* btb = xbf + (size_t)Nn * IN_CH;          // NPACK*IN_CH bf16
  int* counts   = (int*)(btb + (size_t)NPACK * IN_CH);  // Nn ┐
  int* counts2  = counts + Nn;                          // Nn │ single
  float* gsum   = (float*)(counts2 + Nn);               // HC │ memset
  float* gsq    = gsum + HC;                            // HC │ region
  int* flagsA   = (int*)(gsq + HC);                     // 128│
  int* flagsB   = flagsA + 128;                         // 128│
  int* bnctr    = flagsB + 128;                         // 64 ┘ (padded)
  int* offsets  = bnctr + 64;           // Nn
  int* cursor   = offsets + Nn;         // Nn
  int* offsets2 = cursor + Nn;          // Nn
  int* cursor2  = offsets2 + Nn;        // Nn
  int* csr_src  = cursor2 + Nn;         // E
  int2* csr_te  = (int2*)(csr_src + E); // EL int2 (target, eid)
  float* aScale = (float*)(csr_te + EL);   // HC
  float* bShift = aScale + HC;             // HC
  uint8_t* agg8 = (uint8_t*)xbf;  // fp8 agg in dead GEMM-input region (10.2 MB)

  const int nb  = (Nn + 255) / 256;           // scan blocks per CSR (79)
  const int nbc = (Nn * IN_CH / 4 + 255) / 256;
  const int nbp = (NPACK * IN_CH + 255) / 256;
  const int nbh = (E + 255) / 256;
  const int nbh2 = (EL + 255) / 256;

  // 0) one memset: counts | counts2 | gsum | gsq | flagsA | flagsB | bnctr
  (void)hipMemsetAsync(counts, 0, (2 * (size_t)Nn + 2 * HC + 320) * sizeof(int), stream);

  // 1) fused prep: cast + pack + both histograms
  prep<<<nbc + nbp + nbh + nbh2, 256, 0, stream>>>(
      x, xbf, W_l, W_r, btb, ei, counts, eli, counts2,
      Nn * IN_CH / 4, E, EL, nbc, nbp, nbh);

  // 2) one bf16 MFMA GEMM -> xl8 (fp8) | xrb (bf16)
  gemm_mfma<<<632, 512, 0, stream>>>(xbf, btb, xl8, xrb, Nn);

  // 3) dual-CSR scan (lookback) + separate wide fill
  scan_fused<<<2 * nb, 256, 0, stream>>>(counts, offsets, cursor, flagsA,
                                         counts2, offsets2, cursor2, flagsB, Nn, nb);
  csr_fill<<<nbh + nbh2, 256, 0, stream>>>(ei, cursor, csr_src,
                                           eli, cursor2, csr_te, E, EL, nbh);

  // 4) fused attention + BN stats -> agg8 (fp8) + aScale/bShift
  gatv2_agg<<<(Nn + 3) / 4, 256, 0, stream>>>(xl8, xrb, att, offsets, counts,
                                              csr_src, agg8, gsum, gsq, bnctr,
                                              gamma, beta, aScale, bShift,
                                              1.0f / (float)Nn, Nn);

  // 5) link scoring: fp8 agg gathers + inline BN
  score_g<<<(Nn + 3) / 4, 256, 0, stream>>>(agg8, aScale, bShift, offsets2,
                                            counts2, csr_te, out, Nn);
}

// Round 15
// 270.412 us; speedup vs baseline: 1.3884x; 1.3884x over previous
//
#include <hip/hip_runtime.h>
#include <hip/hip_bf16.h>
#include <cstdint>

#define IN_CH 512
#define HC    512   // HEADS*CH
#define HEADS 8
#define NPACK 1024  // W_l | W_r packed

typedef __attribute__((ext_vector_type(8))) short bf16x8;
typedef __attribute__((ext_vector_type(8))) ushort u16x8;
typedef __attribute__((ext_vector_type(4))) float f32x4;
typedef __attribute__((ext_vector_type(2))) float f32x2;
typedef const __attribute__((address_space(1))) uint8_t* gaddr_t;
typedef __attribute__((address_space(3))) uint8_t* laddr_t;

__device__ inline ushort f2bf(float f) {  // round-to-nearest-even
  uint32_t u = __float_as_uint(f);
  return (ushort)((u + 0x7fffu + ((u >> 16) & 1u)) >> 16);
}
__device__ inline float bf2f(ushort u) {
  return __uint_as_float(((uint32_t)u) << 16);
}

// ---- fp8 e4m3 (OCP) encode/decode: HW cvt ops on gfx950, ALU fallback ------
#if defined(__has_builtin)
#if __has_builtin(__builtin_amdgcn_cvt_pk_f32_fp8) && __has_builtin(__builtin_amdgcn_cvt_pk_fp8_f32)
#define HAVE_HW_FP8 1
#endif
#if __has_builtin(__builtin_elementwise_max)
#define HAVE_EW_MAX 1
#endif
#endif

__device__ __forceinline__ float fp8_decode_sw(uint32_t v) {
  const uint32_t t = v & 0x7fu;
  float m;
  if (t >= 8u) m = __uint_as_float((((t >> 3) + 120u) << 23) | ((t & 7u) << 20));
  else m = (float)t * 0.001953125f;  // subnormal: t * 2^-9
  return (v & 0x80u) ? -m : m;
}
__device__ __forceinline__ uint8_t fp8_encode_sw(float f) {
  const uint32_t b = __float_as_uint(f);
  const uint32_t s = (b >> 24) & 0x80u;
  uint32_t a = b & 0x7fffffffu;
  if (a >= 0x43e00000u) return (uint8_t)(s | 0x7eu);  // saturate to 448
  if (a < 0x3c800000u) {                              // subnormal (< 2^-6)
    const int qi = (int)(__uint_as_float(a) * 512.0f + 0.5f);
    return (uint8_t)(s | (qi >= 8 ? 8u : (uint32_t)qi));
  }
  const uint32_t r = a + 0x7ffffu + ((a >> 20) & 1u);  // RNE to 3-bit mantissa
  const uint32_t e = r >> 23;
  if (e > 135u) return (uint8_t)(s | 0x7eu);
  return (uint8_t)(s | ((e - 120u) << 3) | ((r >> 20) & 7u));
}

// decode 2 fp8 (low/high half-word of u) straight into a packed f32x2.
// HI must be a compile-time constant: the builtin requires an immediate.
template<bool HI>
__device__ __forceinline__ f32x2 fp8x2_dec(uint32_t u) {
#ifdef HAVE_HW_FP8
  return __builtin_amdgcn_cvt_pk_f32_fp8(u, HI);
#else
  const uint32_t w = HI ? (u >> 16) : u;
  f32x2 r;
  r.x = fp8_decode_sw(w & 0xffu);
  r.y = fp8_decode_sw((w >> 8) & 0xffu);
  return r;
#endif
}
__device__ __forceinline__ uint8_t f32_to_fp8(float f) {
#ifdef HAVE_HW_FP8
  return (uint8_t)(__builtin_amdgcn_cvt_pk_fp8_f32(f, f, 0, false) & 0xff);
#else
  return fp8_encode_sw(f);
#endif
}
// pack two f32x2 -> 4 fp8 bytes in one u32
__device__ __forceinline__ uint32_t fp8x4_pack(f32x2 a, f32x2 b) {
#ifdef HAVE_HW_FP8
  uint32_t w = __builtin_amdgcn_cvt_pk_fp8_f32(a.x, a.y, 0, false);
  w = __builtin_amdgcn_cvt_pk_fp8_f32(b.x, b.y, w, true);
  return w;
#else
  return (uint32_t)fp8_encode_sw(a.x) | ((uint32_t)fp8_encode_sw(a.y) << 8) |
         ((uint32_t)fp8_encode_sw(b.x) << 16) | ((uint32_t)fp8_encode_sw(b.y) << 24);
#endif
}

// packed 2xf32 max -> v_pk_max_f32
__device__ __forceinline__ f32x2 pk_max(f32x2 a, f32x2 b) {
#ifdef HAVE_EW_MAX
  return __builtin_elementwise_max(a, b);
#else
  f32x2 r; r.x = fmaxf(a.x, b.x); r.y = fmaxf(a.y, b.y); return r;
#endif
}

// DPP cross-lane add: pure-VALU butterfly step.
template<int CTRL>
__device__ __forceinline__ float dpp_add(float s) {
  const int t = __builtin_amdgcn_update_dpp(0, __float_as_int(s), CTRL, 0xf, 0xf, true);
  return s + __int_as_float(t);
}

// ---- fused prep: cast x->bf16 | pack W^T bf16 | hist(dst) | hist(label s) --
__global__ void prep(const float* __restrict__ x, ushort* __restrict__ xb,
                     const float* __restrict__ Wl, const float* __restrict__ Wr,
                     ushort* __restrict__ bt,
                     const int* __restrict__ ei, int* __restrict__ counts,
                     const int* __restrict__ eli, int* __restrict__ counts2,
                     int n4, int E, int EL, int nbc, int nbp, int nbh) {
  const int b = blockIdx.x;
  if (b < nbc) {
    const int i = b * 256 + threadIdx.x;
    if (i < n4) {
      const float4 v = ((const float4*)x)[i];
      ushort4 o;
      o.x = f2bf(v.x); o.y = f2bf(v.y); o.z = f2bf(v.z); o.w = f2bf(v.w);
      ((ushort4*)xb)[i] = o;
    }
  } else if (b < nbc + nbp) {
    const int i = (b - nbc) * 256 + threadIdx.x;
    if (i < NPACK * IN_CH) {
      const int n = i >> 9, k = i & 511;
      const float v = (n < HC) ? Wl[(size_t)k * HC + n] : Wr[(size_t)k * HC + (n - HC)];
      bt[i] = f2bf(v);
    }
  } else if (b < nbc + nbp + nbh) {
    const int e = (b - nbc - nbp) * 256 + threadIdx.x;
    if (e < E) atomicAdd(&counts[ei[E + e]], 1);
  } else {
    const int e = (b - nbc - nbp - nbh) * 256 + threadIdx.x;
    if (e < EL) atomicAdd(&counts2[eli[e]], 1);
  }
}

// ---- bf16 MFMA GEMM: [M,1024] = xb[M,512] @ Bt^T ---------------------------
// R14 (kept, MATCHED): 256x128 tiles, 8 waves, 3-buf counted-vmcnt ring,
// XCD-chunk swizzle (632 = 8*79 bijective).
__global__ __launch_bounds__(512) void gemm_mfma(
    const ushort* __restrict__ xb, const ushort* __restrict__ bt,
    uint8_t* __restrict__ xl8, ushort* __restrict__ xrb, int M) {
  __shared__ __align__(16) ushort As[3][256 * 32];  // 48 KB ring
  __shared__ __align__(16) ushort Bs[3][128 * 32];  // 24 KB ring
  const int sw  = (blockIdx.x & 7) * 79 + (blockIdx.x >> 3);
  const int row0 = (sw >> 3) * 256;
  const int col0 = (sw & 7) * 128;
  const int wave = threadIdx.x >> 6, lane = threadIdx.x & 63;
  const int quad = lane >> 4, m16 = lane & 15;
  const int wrow = (wave >> 1) * 64;
  const int wcol = (wave & 1) * 64;
  const int srow = lane >> 2;
  const int scol = (lane & 3) * 8;
  const f32x4 zero = {0.f, 0.f, 0.f, 0.f};
  f32x4 acc[4][4];
  #pragma unroll
  for (int i = 0; i < 4; ++i)
    #pragma unroll
    for (int j = 0; j < 4; ++j) acc[i][j] = zero;

  auto stage = [&](int buf, int kt) {  // 3 VMEM instrs per wave
    const int k0 = kt * 32;
    const int r = wave * 16 + srow;
    const ushort* ga0 = xb + (size_t)(row0 + r) * IN_CH + k0 + scol;
    __builtin_amdgcn_global_load_lds((gaddr_t)ga0, (laddr_t)(&As[buf][(wave * 16) * 32]), 16, 0, 0);
    const ushort* ga1 = xb + (size_t)(row0 + 128 + r) * IN_CH + k0 + scol;
    __builtin_amdgcn_global_load_lds((gaddr_t)ga1, (laddr_t)(&As[buf][(128 + wave * 16) * 32]), 16, 0, 0);
    const ushort* gb = bt + (size_t)(col0 + r) * IN_CH + k0 + scol;
    __builtin_amdgcn_global_load_lds((gaddr_t)gb, (laddr_t)(&Bs[buf][(wave * 16) * 32]), 16, 0, 0);
  };
  auto compute = [&](int buf) {
    bf16x8 af[4], bfr[4];
    #pragma unroll
    for (int i = 0; i < 4; ++i)
      af[i] = *(const bf16x8*)(&As[buf][(wrow + i * 16 + m16) * 32 + quad * 8]);
    #pragma unroll
    for (int j = 0; j < 4; ++j)
      bfr[j] = *(const bf16x8*)(&Bs[buf][(wcol + j * 16 + m16) * 32 + quad * 8]);
    #pragma unroll
    for (int i = 0; i < 4; ++i)
      #pragma unroll
      for (int j = 0; j < 4; ++j)
        acc[i][j] = __builtin_amdgcn_mfma_f32_16x16x32_bf16(af[i], bfr[j], acc[i][j], 0, 0, 0);
  };

  stage(0, 0);
  stage(1, 1);
  int buf = 0;
  for (int kt = 0; kt <= 13; ++kt) {
    asm volatile("s_waitcnt vmcnt(3)" ::: "memory");
    __builtin_amdgcn_s_barrier();
    int nbuf = buf + 2; if (nbuf >= 3) nbuf -= 3;
    stage(nbuf, kt + 2);
    compute(buf);
    ++buf; if (buf == 3) buf = 0;
  }
  asm volatile("s_waitcnt vmcnt(3)" ::: "memory");
  __builtin_amdgcn_s_barrier();
  compute(buf);
  ++buf; if (buf == 3) buf = 0;
  asm volatile("s_waitcnt vmcnt(0)" ::: "memory");
  __builtin_amdgcn_s_barrier();
  compute(buf);

  const bool isL = (col0 < HC);
  if (isL) {
    #pragma unroll
    for (int i = 0; i < 4; ++i) {
      const int r = row0 + wrow + i * 16 + quad * 4;
      #pragma unroll
      for (int j = 0; j < 4; ++j) {
        const int cg = col0 + wcol + j * 16 + m16;
        #pragma unroll
        for (int t = 0; t < 4; ++t) {
          const int rr = r + t;
          if (rr < M) xl8[(size_t)rr * HC + cg] = f32_to_fp8(acc[i][j][t]);
        }
      }
    }
  } else {
    const int cbase = col0 - HC;
    #pragma unroll
    for (int i = 0; i < 4; ++i) {
      const int r = row0 + wrow + i * 16 + quad * 4;
      #pragma unroll
      for (int j = 0; j < 4; ++j) {
        const int cg = cbase + wcol + j * 16 + m16;
        #pragma unroll
        for (int t = 0; t < 4; ++t) {
          const int rr = r + t;
          if (rr < M) xrb[(size_t)rr * HC + cg] = f2bf(acc[i][j][t]);
        }
      }
    }
  }
}

// ---- fused dual-CSR exclusive scan (standalone; merged version regressed) --
__global__ __launch_bounds__(256) void scan_fused(
    const int* __restrict__ cA, int* __restrict__ oA, int* __restrict__ curA,
    int* __restrict__ fA,
    const int* __restrict__ cB, int* __restrict__ oB, int* __restrict__ curB,
    int* __restrict__ fB, int Nn, int nb) {
  const int half = (blockIdx.x >= nb) ? 1 : 0;
  const int blk  = blockIdx.x - half * nb;
  const int* counts = half ? cB : cA;
  int* offsets = half ? oB : oA;
  int* cursor  = half ? curB : curA;
  int* flags   = half ? fB : fA;
  __shared__ int tmp[256];
  __shared__ int sPref;
  const int t = threadIdx.x;
  const int i = blk * 256 + t;
  const int v = (i < Nn) ? counts[i] : 0;
  tmp[t] = v;
  __syncthreads();
  for (int d = 1; d < 256; d <<= 1) {
    int add = (t >= d) ? tmp[t - d] : 0;
    __syncthreads();
    tmp[t] += add;
    __syncthreads();
  }
  if (t == 0) atomicExch(&flags[blk], tmp[255] + 1);  // publish aggregate
  if (t < 64) {
    int s = 0;
    for (int b = t; b < blk; b += 64) {
      int f;
      do { f = atomicOr(&flags[b], 0); } while (f == 0);
      s += f - 1;
    }
    #pragma unroll
    for (int off = 32; off > 0; off >>= 1) s += __shfl_down(s, off, 64);
    if (t == 0) sPref = s;
  }
  __syncthreads();
  const int pref = sPref;
  if (i < Nn) {
    const int o = tmp[t] - v + pref;  // exclusive prefix
    offsets[i] = o;
    cursor[i] = o;
  }
}

// 1-edge-per-thread fill (1642 blocks); label CSR packed int2.
__global__ void csr_fill(const int* __restrict__ ei, int* __restrict__ cursor,
                         int* __restrict__ csr_src,
                         const int* __restrict__ eli, int* __restrict__ cursor2,
                         int2* __restrict__ csr_te, int E, int EL, int nbE) {
  const int b = blockIdx.x;
  if (b < nbE) {
    const int e = b * 256 + threadIdx.x;
    if (e < E) {
      const int pos = atomicAdd(&cursor[ei[E + e]], 1);
      csr_src[pos] = ei[e];
    }
  } else {
    const int e = (b - nbE) * 256 + threadIdx.x;
    if (e < EL) {
      const int pos = atomicAdd(&cursor2[eli[e]], 1);
      csr_te[pos] = make_int2(eli[EL + e], e);
    }
  }
}

// ------- fused GATv2: logits + softmax + aggregation, 1 wave/node -----------
// R19 (BEST, 271.9us): per-node blocks (measured floor), fp8 gather of xl8,
// fp8 agg8 output (halves score_g/bn_stats bytes, no extra dispatch).
// R20's in-kernel BN-stats fusion regressed 4.4x (LDS-atomic contention +
// 5000-way global atomic contention) -- reverted to standalone bn_stats.
__global__ __launch_bounds__(256) void gatv2_agg(
    const uint8_t* __restrict__ xl8, const ushort* xrb, const float* __restrict__ att,
    const int* __restrict__ offsets, const int* __restrict__ counts,
    const int* __restrict__ csr_src, uint8_t* __restrict__ agg8, int Nn) {
  const int node = blockIdx.x * 4 + (threadIdx.x >> 6);
  const int lane = threadIdx.x & 63;
  if (node >= Nn) return;
  const int start = offsets[node];
  const int deg   = counts[node];
  uint2* pd = (uint2*)(agg8 + (size_t)node * HC + lane * 8);
  if (deg == 0) {  // must still write zeros: agg8 is consumed for all nodes
    const uint2 z = {0u, 0u};
    *pd = z;
    return;
  }
  f32x2 rv2[4], tv2[4];
  {
    const u16x8 ur = *(const u16x8*)(xrb + (size_t)node * HC + lane * 8);
    #pragma unroll
    for (int c = 0; c < 4; ++c) {
      rv2[c].x = bf2f((ushort)ur[2 * c]);
      rv2[c].y = bf2f((ushort)ur[2 * c + 1]);
    }
    const float4* pa = (const float4*)(att + lane * 8);
    const float4 t0 = pa[0], t1 = pa[1];
    tv2[0].x = t0.x; tv2[0].y = t0.y;
    tv2[1].x = t0.z; tv2[1].y = t0.w;
    tv2[2].x = t1.x; tv2[2].y = t1.y;
    tv2[3].x = t1.z; tv2[3].y = t1.w;
  }
  f32x2 acc2[4] = {{0.f, 0.f}, {0.f, 0.f}, {0.f, 0.f}, {0.f, 0.f}};
  float densum = 0.f;
  const int* ps = csr_src + start;
  auto row = [&](int idx) {
    return *(const uint2*)(xl8 + (size_t)ps[idx] * HC + lane * 8);
  };
  auto body = [&](const uint2 cur) {
    f32x2 a0 = fp8x2_dec<false>(cur.x);
    f32x2 a1 = fp8x2_dec<true>(cur.x);
    f32x2 a2 = fp8x2_dec<false>(cur.y);
    f32x2 a3 = fp8x2_dec<true>(cur.y);
    f32x2 v, s2;
    v = a0 + rv2[0]; s2  = pk_max(v, 0.2f * v) * tv2[0];  // leaky_relu
    v = a1 + rv2[1]; s2 += pk_max(v, 0.2f * v) * tv2[1];
    v = a2 + rv2[2]; s2 += pk_max(v, 0.2f * v) * tv2[2];
    v = a3 + rv2[3]; s2 += pk_max(v, 0.2f * v) * tv2[3];
    float s = s2.x + s2.y;
    s = dpp_add<0xB1>(s);    // xor1
    s = dpp_add<0x4E>(s);    // xor2
    s = dpp_add<0x141>(s);   // xor4 (row_half_mirror)
    const float ea = __expf(s);
    densum += ea;
    const f32x2 eav = {ea, ea};
    acc2[0] += eav * a0;
    acc2[1] += eav * a1;
    acc2[2] += eav * a2;
    acc2[3] += eav * a3;
  };

  // depth-2 prefetch (measured best, R8)
  uint2 b0 = {}, b1 = {};
  b0 = row(0);
  if (deg > 1) b1 = row(1);
  int i = 0;
  for (; i + 2 <= deg; i += 2) {
    const uint2 c0 = b0;
    if (i + 2 < deg) b0 = row(i + 2);
    const uint2 c1 = b1;
    if (i + 3 < deg) b1 = row(i + 3);
    body(c0);
    body(c1);
  }
  if (i < deg) body(b0);

  const float inv = 1.0f / (densum + 1e-16f);
  const f32x2 iv = {inv, inv};
  uint2 pack;
  pack.x = fp8x4_pack(acc2[0] * iv, acc2[1] * iv);
  pack.y = fp8x4_pack(acc2[2] * iv, acc2[3] * iv);
  *pd = pack;
}

// ------------- BatchNorm stats + last-block finalize (fp8 agg) --------------
__global__ void bn_stats(const uint8_t* __restrict__ agg8, float* __restrict__ gsum,
                         float* __restrict__ gsq, int* __restrict__ ctr,
                         const float* __restrict__ gamma, const float* __restrict__ beta,
                         float* __restrict__ aScale, float* __restrict__ bShift,
                         float invN, int Nn) {
  const int t = threadIdx.x;  // 256; thread covers channels 2t, 2t+1
  const int rows_per_block = (Nn + gridDim.x - 1) / gridDim.x;
  const int r0 = blockIdx.x * rows_per_block;
  const int r1 = min(Nn, r0 + rows_per_block);
  float s0 = 0.f, s1 = 0.f, q0 = 0.f, q1 = 0.f;
  for (int r = r0; r < r1; ++r) {
    const uchar2 u = ((const uchar2*)(agg8 + (size_t)r * HC))[t];
    const f32x2 v = fp8x2_dec<false>((uint32_t)u.x | ((uint32_t)u.y << 8));
    s0 += v.x; q0 += v.x * v.x;
    s1 += v.y; q1 += v.y * v.y;
  }
  atomicAdd(&gsum[2 * t], s0);
  atomicAdd(&gsum[2 * t + 1], s1);
  atomicAdd(&gsq[2 * t], q0);
  atomicAdd(&gsq[2 * t + 1], q1);
  __shared__ int isLast;
  __syncthreads();
  if (t == 0) {
    __threadfence();
    isLast = (atomicAdd(ctr, 1) == (int)gridDim.x - 1) ? 1 : 0;
  }
  __syncthreads();
  if (isLast) {
    #pragma unroll
    for (int k = 0; k < 2; ++k) {
      const int c = t + k * 256;
      const float sum = atomicAdd(&gsum[c], 0.0f);  // coherent read
      const float sq  = atomicAdd(&gsq[c], 0.0f);
      const float m = sum * invN;
      const float var = sq * invN - m * m;
      const float rs = rsqrtf(var + 1e-5f);
      const float a = rs * gamma[c];
      aScale[c] = a;
      bShift[c] = beta[c] - m * a;
    }
  }
}

// ------------- source-grouped link scoring: fp8 agg + inline BN -------------
// R19: gathers agg8 (8 B/lane, half of bf16) + packed-f32 BN+ReLU+dot.
__global__ __launch_bounds__(256) void score_g(
    const uint8_t* __restrict__ agg8, const float* __restrict__ aScale,
    const float* __restrict__ bShift, const int* __restrict__ off2,
    const int* __restrict__ cnt2, const int2* __restrict__ csr_te,
    float* __restrict__ out, int Nn) {
  const int node = blockIdx.x * 4 + (threadIdx.x >> 6);
  const int lane = threadIdx.x & 63;
  if (node >= Nn) return;
  const int start = off2[node];
  const int deg   = cnt2[node];
  if (deg == 0) return;
  const f32x2 z2 = {0.f, 0.f};
  f32x2 aS2[4], bS2[4], ys2[4];
  {
    const float4* pa = (const float4*)(aScale + lane * 8);
    const float4 a0 = pa[0], a1 = pa[1];
    aS2[0].x=a0.x; aS2[0].y=a0.y; aS2[1].x=a0.z; aS2[1].y=a0.w;
    aS2[2].x=a1.x; aS2[2].y=a1.y; aS2[3].x=a1.z; aS2[3].y=a1.w;
    const float4* pb = (const float4*)(bShift + lane * 8);
    const float4 c0 = pb[0], c1 = pb[1];
    bS2[0].x=c0.x; bS2[0].y=c0.y; bS2[1].x=c0.z; bS2[1].y=c0.w;
    bS2[2].x=c1.x; bS2[2].y=c1.y; bS2[3].x=c1.z; bS2[3].y=c1.w;
    const uint2 us = *(const uint2*)(agg8 + (size_t)node * HC + lane * 8);
    ys2[0] = pk_max(z2, fp8x2_dec<false>(us.x) * aS2[0] + bS2[0]);
    ys2[1] = pk_max(z2, fp8x2_dec<true>(us.x)  * aS2[1] + bS2[1]);
    ys2[2] = pk_max(z2, fp8x2_dec<false>(us.y) * aS2[2] + bS2[2]);
    ys2[3] = pk_max(z2, fp8x2_dec<true>(us.y)  * aS2[3] + bS2[3]);
  }
  const int2* pte = csr_te + start;
  auto row = [&](int idx) {
    return *(const uint2*)(agg8 + (size_t)pte[idx].x * HC + lane * 8);
  };
  auto emit = [&](const uint2 ut, int eid) {
    f32x2 s2;
    s2  = ys2[0] * pk_max(z2, fp8x2_dec<false>(ut.x) * aS2[0] + bS2[0]);
    s2 += ys2[1] * pk_max(z2, fp8x2_dec<true>(ut.x)  * aS2[1] + bS2[1]);
    s2 += ys2[2] * pk_max(z2, fp8x2_dec<false>(ut.y) * aS2[2] + bS2[2]);
    s2 += ys2[3] * pk_max(z2, fp8x2_dec<true>(ut.y)  * aS2[3] + bS2[3]);
    float s = s2.x + s2.y;
    s = dpp_add<0xB1>(s);    // xor1
    s = dpp_add<0x4E>(s);    // xor2
    s = dpp_add<0x141>(s);   // xor4 (row_half_mirror)
    s = dpp_add<0x140>(s);   // xor8 (row_mirror) -> all lanes hold row16 sum
    s = dpp_add<0x142>(s);   // row_bcast15: row1+=row0, row3+=row2
    s = dpp_add<0x143>(s);   // row_bcast31: hi half += lane31 -> lane63 total
    if (lane == 63) out[eid] = s;
  };
  uint2 b0 = {}, b1 = {};
  b0 = row(0);
  if (deg > 1) b1 = row(1);
  int j = 0;
  for (; j + 2 <= deg; j += 2) {
    const uint2 c0 = b0;
    if (j + 2 < deg) b0 = row(j + 2);
    const uint2 c1 = b1;
    if (j + 3 < deg) b1 = row(j + 3);
    emit(c0, pte[j].y);
    emit(c1, pte[j + 1].y);
  }
  if (j < deg) emit(b0, pte[j].y);
}

extern "C" void kernel_launch(void* const* d_in, const int* in_sizes, int n_in,
                              void* d_out, int out_size, void* d_ws, size_t ws_size,
                              hipStream_t stream) {
  const float* x     = (const float*)d_in[0];
  const int*   ei    = (const int*)d_in[1];
  const int*   eli   = (const int*)d_in[2];
  const float* W_l   = (const float*)d_in[3];
  const float* W_r   = (const float*)d_in[4];
  const float* att   = (const float*)d_in[5];
  // d_in[6] = bias: cancels exactly inside train-mode BatchNorm -> unused.
  const float* gamma = (const float*)d_in[7];
  const float* beta  = (const float*)d_in[8];
  float* out = (float*)d_out;

  const int Nn = in_sizes[0] / IN_CH;  // 20000
  const int E  = in_sizes[1] / 2;      // 320000
  const int EL = in_sizes[2] / 2;      // 100000

  // ---- workspace layout -----------------------------------------------------
  uint8_t* xl8 = (uint8_t*)d_ws;                   // Nn*HC fp8 (region sized Nn*HC*2B)
  ushort* xrb = (ushort*)d_ws + (size_t)Nn * HC;   // Nn*HC bf16 (gatv2 input)
  ushort* xbf = xrb + (size_t)Nn * HC;             // Nn*IN_CH bf16 (dead after gemm)
  ushort* btb = xbf + (size_t)Nn * IN_CH;          // NPACK*IN_CH bf16
  int* counts   = (int*)(btb + (size_t)NPACK * IN_CH);  // Nn ┐
  int* counts2  = counts + Nn;                          // Nn │ single
  float* gsum   = (float*)(counts2 + Nn);               // HC │ memset
  float* gsq    = gsum + HC;                            // HC │ region
  int* flagsA   = (int*)(gsq + HC);                     // 128│
  int* flagsB   = flagsA + 128;                         // 128│
  int* bnctr    = flagsB + 128;                         // 64 ┘ (padded)
  int* offsets  = bnctr + 64;           // Nn
  int* cursor   = offsets + Nn;         // Nn
  int* offsets2 = cursor + Nn;          // Nn
  int* cursor2  = offsets2 + Nn;        // Nn
  int* csr_src  = cursor2 + Nn;         // E
  int2* csr_te  = (int2*)(csr_src + E); // EL int2 (target, eid)
  float* aScale = (float*)(csr_te + EL);   // HC
  float* bShift = aScale + HC;             // HC
  uint8_t* agg8 = (uint8_t*)xbf;  // fp8 agg in dead GEMM-input region (10.2 MB)

  const int nb  = (Nn + 255) / 256;           // scan blocks per CSR (79)
  const int nbc = (Nn * IN_CH / 4 + 255) / 256;
  const int nbp = (NPACK * IN_CH + 255) / 256;
  const int nbh = (E + 255) / 256;
  const int nbh2 = (EL + 255) / 256;

  // 0) one memset: counts | counts2 | gsum | gsq | flagsA | flagsB | bnctr
  (void)hipMemsetAsync(counts, 0, (2 * (size_t)Nn + 2 * HC + 320) * sizeof(int), stream);

  // 1) fused prep: cast + pack + both histograms
  prep<<<nbc + nbp + nbh + nbh2, 256, 0, stream>>>(
      x, xbf, W_l, W_r, btb, ei, counts, eli, counts2,
      Nn * IN_CH / 4, E, EL, nbc, nbp, nbh);

  // 2) one bf16 MFMA GEMM -> xl8 (fp8) | xrb (bf16)
  gemm_mfma<<<632, 512, 0, stream>>>(xbf, btb, xl8, xrb, Nn);

  // 3) dual-CSR scan (lookback) + separate wide fill
  scan_fused<<<2 * nb, 256, 0, stream>>>(counts, offsets, cursor, flagsA,
                                         counts2, offsets2, cursor2, flagsB, Nn, nb);
  csr_fill<<<nbh + nbh2, 256, 0, stream>>>(ei, cursor, csr_src,
                                           eli, cursor2, csr_te, E, EL, nbh);

  // 4) fused attention (per-node blocks, fp8 gather) -> agg8 (fp8)
  gatv2_agg<<<(Nn + 3) / 4, 256, 0, stream>>>(xl8, xrb, att, offsets, counts,
                                              csr_src, agg8, Nn);

  // 5) BN stats + last-block finalize -> aScale/bShift (fp8 reads)
  bn_stats<<<200, 256, 0, stream>>>(agg8, gsum, gsq, bnctr, gamma, beta,
                                    aScale, bShift, 1.0f / (float)Nn, Nn);

  // 6) link scoring: fp8 agg gathers + inline BN
  score_g<<<(Nn + 3) / 4, 256, 0, stream>>>(agg8, aScale, bShift, offsets2,
                                            counts2, csr_te, out, Nn);
}